// Round 5
// baseline (246.934 us; speedup 1.0000x reference)
//
#include <hip/hip_runtime.h>

typedef _Float16 f16_t;
typedef _Float16 f16x4 __attribute__((ext_vector_type(4)));
typedef _Float16 f16x8 __attribute__((ext_vector_type(8)));
typedef short s16x8 __attribute__((ext_vector_type(8)));
typedef unsigned short u16x4 __attribute__((ext_vector_type(4)));
typedef float floatx4 __attribute__((ext_vector_type(4)));

#define NB 8
#define SEQ 1024
#define DIM 768
// 1/sqrt(768)
#define INV_SCALE 0.03608439182435161f
// constant shift for unscaled row softmax (shift-invariant; row maxes ~35).
// e values are stored UNNORMALIZED in bf16 (fp32 exponent range -> no
// underflow for small row maxes); normalization happens in the apply epilogue.
#define ROW_SHIFT 40.0f

// float -> bf16 round-to-nearest-even
__device__ inline unsigned short f2bf(float f) {
  unsigned u = __builtin_bit_cast(unsigned, f);
  u += 0x7fffu + ((u >> 16) & 1u);
  return (unsigned short)(u >> 16);
}

// ---------------------------------------------------------------------------
// async 16B global->LDS; LDS dest = wave-uniform base + lane*16 (m104/m108).
__device__ inline void async_load16(const void* g, void* l) {
  __builtin_amdgcn_global_load_lds((__attribute__((address_space(1))) void*)g,
                                   (__attribute__((address_space(3))) void*)l,
                                   16, 0, 0);
}

// LDS bank-conflict XOR swizzle: logical column group (8 f16 = 16B) g of row
// r is stored at group g ^ (r&7). Async staging applies it to the *global
// source* column (dest is lane-forced); reads apply it to the LDS column.

// ---------------------------------------------------------------------------
// Slim prep: fp16 casts only (proj operands + W). Out-left copy rides under
// gemm_apply; transposes ride under scores. Input blocks use batch==XCD
// decode so lhs_f/rhs_f land in the XCD L2 that gemm_proj reads them from.
__global__ __launch_bounds__(256) void prep(
    const float* __restrict__ lhs, const float* __restrict__ rhs,
    const float* __restrict__ Wl, const float* __restrict__ Wr,
    f16_t* __restrict__ lf, f16_t* __restrict__ rf, f16_t* __restrict__ Wlh,
    f16_t* __restrict__ Wrh) {
  const int which = blockIdx.y;
  const int bx = blockIdx.x;
  const int tid = threadIdx.x;
  if (bx >= 1536) {  // W cast: 768*768 = 147456 float4 = 144 blocks x 4 iters
    const float4* in = (const float4*)(which ? Wr : Wl);
    f16_t* out = which ? Wrh : Wlh;
    #pragma unroll
    for (int it = 0; it < 4; ++it) {
      const int idx = (bx - 1536) * 1024 + it * 256 + tid;
      const float4 v = in[idx];
      *(f16x4*)(out + idx * 4) =
          f16x4{(f16_t)v.x, (f16_t)v.y, (f16_t)v.z, (f16_t)v.w};
    }
    return;
  }
  // inputs: 8 batches x 196608 float4; n = bx&7 (XCD), 192 chunk-blocks/batch
  const int n = bx & 7, c = bx >> 3;
  const float4* in =
      (const float4*)(which ? rhs : lhs) + (size_t)n * 196608 + c * 1024;
  f16_t* out = (which ? rf : lf) + (size_t)n * SEQ * DIM + c * 4096;
  #pragma unroll
  for (int it = 0; it < 4; ++it) {
    const int idx = it * 256 + tid;
    const float4 v = in[idx];
    *(f16x4*)(out + idx * 4) =
        f16x4{(f16_t)v.x, (f16_t)v.y, (f16_t)v.z, (f16_t)v.w};
  }
}

// ---------------------------------------------------------------------------
// Projection GEMM (plain fp16, async-staged): C = tanh(A[M,K] @ W[N,K]^T),
// fp16 out. Decode: batch n == XCD (b&7) so l_f/r_f[n] are produced on the
// XCD that gemm_scores will consume them on (and prep wrote lhs_f there).
__global__ __launch_bounds__(256, 3) void gemm_proj(
    const f16_t* __restrict__ A0, const f16_t* __restrict__ W0,
    const f16_t* __restrict__ A1, const f16_t* __restrict__ W1,
    f16_t* __restrict__ C0, f16_t* __restrict__ C1) {
  __shared__ __align__(16) f16_t sA[128 * 64];
  __shared__ __align__(16) f16_t sB[128 * 64];
  const int b = blockIdx.x;  // 768 = 8n * 2side * 8myb * 6j
  const int n = b & 7;       // XCD
  const int s = b >> 3;      // 0..95
  const int side = s / 48;
  const int t = s - side * 48;
  const int myb = t / 6, j = t - myb * 6;
  const int my = n * 8 + myb;  // 0..63 (8192 rows / 128)
  const f16_t* Ab = (side ? A1 : A0) + (size_t)my * 128 * DIM;
  const f16_t* Bb = (side ? W1 : W0) + (size_t)j * 128 * DIM;
  f16_t* C = side ? C1 : C0;
  const int tid = threadIdx.x;
  const int lane = tid & 63;
  const int wave = tid >> 6;
  const int wr = wave >> 1, wc = wave & 1;
  const int fr = lane & 15;
  const int fq = lane >> 4;
  const int swz = ((lane & 7) ^ (lane >> 3)) << 3;  // staging src column
  const int x7 = (fr & 7) << 3;                     // read-side XOR

  floatx4 acc[4][4] = {};

  for (int kt = 0; kt < DIM; kt += 64) {
    #pragma unroll
    for (int i = 0; i < 4; ++i) {
      const int ch = i * 4 + wave;
      const int row = ch * 8 + (lane >> 3);
      const size_t g = (size_t)row * DIM + kt + swz;
      async_load16(Ab + g, (char*)sA + ch * 1024);
      async_load16(Bb + g, (char*)sB + ch * 1024);
    }
    __syncthreads();
    #pragma unroll
    for (int ks = 0; ks < 64; ks += 32) {
      f16x8 af[4], bf[4];
      #pragma unroll
      for (int t2 = 0; t2 < 4; ++t2) {
        const int cs = (ks + fq * 8) ^ x7;
        af[t2] = *(const f16x8*)&sA[(wr * 64 + t2 * 16 + fr) * 64 + cs];
        bf[t2] = *(const f16x8*)&sB[(wc * 64 + t2 * 16 + fr) * 64 + cs];
      }
      #pragma unroll
      for (int ti = 0; ti < 4; ++ti)
        #pragma unroll
        for (int tj = 0; tj < 4; ++tj)
          acc[ti][tj] = __builtin_amdgcn_mfma_f32_16x16x32_f16(
              af[ti], bf[tj], acc[ti][tj], 0, 0, 0);
    }
    __syncthreads();
  }

  // C/D layout (m89/m91): col = lane&15, row = (lane>>4)*4 + reg
  const size_t m0 = (size_t)my * 128, n0 = (size_t)j * 128;
  #pragma unroll
  for (int ti = 0; ti < 4; ++ti)
    #pragma unroll
    for (int tj = 0; tj < 4; ++tj) {
      const size_t gm = m0 + wr * 64 + ti * 16 + fq * 4;
      const size_t gn = n0 + wc * 64 + tj * 16 + fr;
      #pragma unroll
      for (int i = 0; i < 4; ++i) {
        // tanh(x) = 1 - 2/(e^{2x}+1); exact at +-inf, ~1ulp via v_rcp (fp16
        // output swallows the error). Avoids branchy libm tanhf.
        const float e = __expf(2.f * acc[ti][tj][i]);
        C[(gm + i) * DIM + gn] =
            (f16_t)(1.f - 2.f * __builtin_amdgcn_rcpf(e + 1.f));
      }
    }
}

// ---------------------------------------------------------------------------
// Mixed launch: b<512 -> scores GEMM (batch z == XCD: whole batch working set
// l_f[z]+r_f[z] = 3MB is L2-resident per XCD); b>=512 -> input transposes
// (lhsT fp16 / rhsT bf16), rider batch n == XCD (b&7) so the T-panels are
// written on the XCD L2 that gemm_apply reads them from.
// Scores epilogue writes UNNORMALIZED exponentials: e_l bf16 row-major
// (direct), e_rT fp16 via LDS transpose (coalesced 16B stores), plus 16-way
// partial row/col sums (finished in gemm_apply's prologue).
__global__ __launch_bounds__(256, 3) void scores_mix(
    const f16_t* __restrict__ A, const f16_t* __restrict__ B,
    const float* __restrict__ lhs32, const float* __restrict__ rhs32,
    unsigned short* __restrict__ e_l, f16_t* __restrict__ e_rT,
    f16_t* __restrict__ lhsT, unsigned short* __restrict__ rhsT,
    float* __restrict__ rowpart, float* __restrict__ colpart) {
  __shared__ __align__(16) char smem[32768];
  const int b = blockIdx.x;
  const int tid = threadIdx.x;

  if (b >= 512) {  // ---- transpose riders: n == XCD (b&7)
    float(*tile)[65] = (float(*)[65])smem;  // 64*65*4 = 16640 B
    const int t = b - 512;                  // 0..255; t&7 == b&7 (512%8==0)
    const int n = t & 7;                    // XCD-aligned batch
    const int side = t >> 7;                // 0: lhs->lhsT, 1: rhs->rhsT
    const int r0 = ((t >> 3) & 15) * 64;
    const float* in = (side ? rhs32 : lhs32) + (size_t)n * SEQ * DIM;
    const int x = tid & 63, y = tid >> 6;
    for (int d0 = 0; d0 < DIM; d0 += 64) {
      #pragma unroll
      for (int yy = y; yy < 64; yy += 4)
        tile[yy][x] = in[(size_t)(r0 + yy) * DIM + d0 + x];
      __syncthreads();
      if (side == 0) {
        f16_t* out = lhsT + (size_t)n * SEQ * DIM;
        #pragma unroll
        for (int yy = y; yy < 64; yy += 4)
          out[(size_t)(d0 + yy) * SEQ + r0 + x] = (f16_t)tile[x][yy];
      } else {
        unsigned short* out = rhsT + (size_t)n * SEQ * DIM;
        #pragma unroll
        for (int yy = y; yy < 64; yy += 4)
          out[(size_t)(d0 + yy) * SEQ + r0 + x] = f2bf(tile[x][yy]);
      }
      __syncthreads();
    }
    return;
  }

  // ---- scores GEMM path
  f16_t* sA = (f16_t*)smem;
  f16_t* sB = sA + 8192;
  const int z = b & 7;   // batch == XCD
  const int s = b >> 3;  // 0..63
  const int my = s >> 3, j = s & 7;
  const f16_t* Ab = A + (size_t)z * SEQ * DIM + (size_t)my * 128 * DIM;
  const f16_t* Bb = B + (size_t)z * SEQ * DIM + (size_t)j * 128 * DIM;
  const int lane = tid & 63;
  const int wave = tid >> 6;
  const int wr = wave >> 1, wc = wave & 1;
  const int fr = lane & 15;
  const int fq = lane >> 4;
  const int swz = ((lane & 7) ^ (lane >> 3)) << 3;
  const int x7 = (fr & 7) << 3;

  floatx4 acc[4][4] = {};

  for (int kt = 0; kt < DIM; kt += 64) {
    #pragma unroll
    for (int i = 0; i < 4; ++i) {
      const int ch = i * 4 + wave;
      const int row = ch * 8 + (lane >> 3);
      const size_t g = (size_t)row * DIM + kt + swz;
      async_load16(Ab + g, (char*)sA + ch * 1024);
      async_load16(Bb + g, (char*)sB + ch * 1024);
    }
    __syncthreads();
    #pragma unroll
    for (int ks = 0; ks < 64; ks += 32) {
      f16x8 af[4], bf[4];
      #pragma unroll
      for (int t2 = 0; t2 < 4; ++t2) {
        const int cs = (ks + fq * 8) ^ x7;
        af[t2] = *(const f16x8*)&sA[(wr * 64 + t2 * 16 + fr) * 64 + cs];
        bf[t2] = *(const f16x8*)&sB[(wc * 64 + t2 * 16 + fr) * 64 + cs];
      }
      #pragma unroll
      for (int ti = 0; ti < 4; ++ti)
        #pragma unroll
        for (int tj = 0; tj < 4; ++tj)
          acc[ti][tj] = __builtin_amdgcn_mfma_f32_16x16x32_f16(
              af[ti], bf[tj], acc[ti][tj], 0, 0, 0);
    }
    __syncthreads();
  }

  const size_t m0 = (size_t)my * 128, n0 = (size_t)j * 128;
  unsigned short* eL = e_l + (size_t)z * SEQ * SEQ;
  f16_t* eT = e_rT + (size_t)z * SEQ * SEQ;

  // row side: e = exp(s - 40) -> bf16 direct store (32B segments) + 16-way
  // partial row sums (axis: j*2+wc), stats entirely in registers.
  #pragma unroll
  for (int ti = 0; ti < 4; ++ti) {
    #pragma unroll
    for (int i = 0; i < 4; ++i) {
      const int rloc = wr * 64 + ti * 16 + fq * 4 + i;
      float sum = 0.f;
      #pragma unroll
      for (int tj = 0; tj < 4; ++tj) {
        const float e = __expf(acc[ti][tj][i] - ROW_SHIFT);
        sum += e;
        eL[(m0 + rloc) * SEQ + n0 + wc * 64 + tj * 16 + fr] = f2bf(e);
      }
      sum += __shfl_xor(sum, 1, 64);
      sum += __shfl_xor(sum, 2, 64);
      sum += __shfl_xor(sum, 4, 64);
      sum += __shfl_xor(sum, 8, 64);
      if (fr == 0)
        rowpart[((size_t)(z * 16 + j * 2 + wc)) * SEQ + m0 + rloc] = sum;
    }
  }
  // col side: e = exp(s * INV_SCALE) -> fp16 into LDS transpose tile
  // (XOR-swizzled), + 16-way partial col sums (axis: my*2+wr).
  #pragma unroll
  for (int tj = 0; tj < 4; ++tj) {
    const int rp = wc * 64 + tj * 16 + fr;  // e_rT-local row (= score col)
    float sum = 0.f;
    #pragma unroll
    for (int ti = 0; ti < 4; ++ti) {
      #pragma unroll
      for (int i = 0; i < 4; ++i) {
        const float e = __expf(acc[ti][tj][i] * INV_SCALE);
        sum += e;
        const int cp = wr * 64 + ti * 16 + fq * 4 + i;  // e_rT-local col
        *(f16_t*)(smem + rp * 256 + ((cp * 2) ^ ((rp & 7) << 4))) = (f16_t)e;
      }
    }
    sum += __shfl_xor(sum, 16, 64);
    sum += __shfl_xor(sum, 32, 64);
    if (fq == 0)
      colpart[((size_t)(z * 16 + my * 2 + wr)) * SEQ + n0 + rp] = sum;
  }
  __syncthreads();
  // coalesced e_rT store: 16 lanes cover one 256B row segment-pair
  #pragma unroll
  for (int it = 0; it < 8; ++it) {
    const int r = it * 16 + (tid >> 4), chunk = tid & 15;
    const f16x8 v =
        *(const f16x8*)(smem + r * 256 + ((chunk * 16) ^ ((r & 7) << 4)));
    *(f16x8*)&eT[(n0 + r) * SEQ + m0 + chunk * 8] = v;
  }
}

// ---------------------------------------------------------------------------
// Apply GEMM body. A = unnormalized exp matrix, B = transposed input, and the
// softmax normalizer (1/sum over 16 partials, per OUTPUT ROW) is applied in
// the epilogue. BF=true -> bf16 MFMA (side 0), else fp16 (side 1).
template <bool BF>
__device__ __forceinline__ void apply_body(
    const f16_t* __restrict__ Ab, const f16_t* __restrict__ Bb,
    float* __restrict__ C, const float* __restrict__ pp, f16_t* sA, f16_t* sB,
    float* sinv) {
  const int tid = threadIdx.x;
  const int lane = tid & 63;
  const int wave = tid >> 6;
  const int wr = wave >> 1, wc = wave & 1;
  const int fr = lane & 15;
  const int fq = lane >> 4;
  const int swz = ((lane & 7) ^ (lane >> 3)) << 3;
  const int x7 = (fr & 7) << 3;

  // finish stats here: 1/sum over 16 partials for this block's 128 out rows.
  if (tid < 128) {
    float s = 0.f;
    #pragma unroll
    for (int k = 0; k < 16; ++k) s += pp[k * SEQ + tid];
    sinv[tid] = 1.f / s;
  }

  floatx4 acc[4][4] = {};

  for (int kt = 0; kt < SEQ; kt += 64) {
    #pragma unroll
    for (int i = 0; i < 4; ++i) {
      const int ch = i * 4 + wave;
      const int row = ch * 8 + (lane >> 3);
      const size_t g = (size_t)row * SEQ + kt + swz;
      async_load16(Ab + g, (char*)sA + ch * 1024);
      async_load16(Bb + g, (char*)sB + ch * 1024);
    }
    __syncthreads();
    #pragma unroll
    for (int ks = 0; ks < 64; ks += 32) {
      const int cs = (ks + fq * 8) ^ x7;
      #pragma unroll
      for (int ti = 0; ti < 4; ++ti) {
        const f16_t* pa = &sA[(wr * 64 + ti * 16 + fr) * 64 + cs];
        #pragma unroll
        for (int tj = 0; tj < 4; ++tj) {
          const f16_t* pb = &sB[(wc * 64 + tj * 16 + fr) * 64 + cs];
          if constexpr (BF)
            acc[ti][tj] = __builtin_amdgcn_mfma_f32_16x16x32_bf16(
                *(const s16x8*)pa, *(const s16x8*)pb, acc[ti][tj], 0, 0, 0);
          else
            acc[ti][tj] = __builtin_amdgcn_mfma_f32_16x16x32_f16(
                *(const f16x8*)pa, *(const f16x8*)pb, acc[ti][tj], 0, 0, 0);
        }
      }
    }
    __syncthreads();
  }

  #pragma unroll
  for (int ti = 0; ti < 4; ++ti) {
    const int gm = wr * 64 + ti * 16 + fq * 4;
    const floatx4 iv = *(const floatx4*)&sinv[gm];
    #pragma unroll
    for (int tj = 0; tj < 4; ++tj) {
      const int gn = wc * 64 + tj * 16 + fr;
      #pragma unroll
      for (int i = 0; i < 4; ++i)
        C[(size_t)(gm + i) * (2 * DIM) + gn] = acc[ti][tj][i] * iv[i];
    }
  }
}

// Decode: batch n == XCD (b&7); both sides of batch n run on XCD n, reading
// e_l/e_rT[n] written there by scores (L2-warm) and keeping the B panels
// (rhsT/lhsT[n], 1.5MB each) L2-resident per XCD. Blocks with slot s>=96
// (ids >= 768, dispatched last -> tail-fill) are out-left copy riders:
// fully-coalesced fp32 row copies of the inputs into the output left halves
// (no in-device consumer, so they can ride under the last launch).
__global__ __launch_bounds__(256, 3) void gemm_apply(
    const f16_t* __restrict__ e_l, const f16_t* __restrict__ e_rT,
    const f16_t* __restrict__ rhsT, const f16_t* __restrict__ lhsT,
    const float* __restrict__ rowpart, const float* __restrict__ colpart,
    const float* __restrict__ lhs32, const float* __restrict__ rhs32,
    float* __restrict__ out0, float* __restrict__ out1) {
  __shared__ __align__(16) f16_t sA[128 * 64];
  __shared__ __align__(16) f16_t sB[128 * 64];
  __shared__ __align__(16) float sinv[128];
  const int b = blockIdx.x;  // 1024 = 8n * (12side*my*j GEMM + 4 rider) slots
  const int n = b & 7;       // XCD
  const int s = b >> 3;      // 0..127
  if (s >= 96) {             // ---- out-left copy riders (n == XCD)
    const int rid = s - 96;  // 0..31
    const int side = rid >> 4;
    const int r0 = (rid & 15) * 64;
    const float* in = (side ? rhs32 : lhs32) + (size_t)n * SEQ * DIM;
    float* oh = (side ? out1 : out0) + (size_t)n * SEQ * 2 * DIM;
    const int w = threadIdx.x >> 6, lane = threadIdx.x & 63;
    for (int r = 0; r < 16; ++r) {
      const int row = r0 + w * 16 + r;
      const float4* src = (const float4*)&in[(size_t)row * DIM];
      float4* dst = (float4*)&oh[(size_t)row * (2 * DIM)];
      #pragma unroll
      for (int i = 0; i < 3; ++i) dst[i * 64 + lane] = src[i * 64 + lane];
    }
    return;
  }
  const int side = s / 48;
  const int t = s - side * 48;
  const int my = t / 6, j = t - my * 6;
  const size_t m0 = (size_t)my * 128, n0 = (size_t)j * 128;
  if (side == 0) {
    apply_body<true>(e_l + (size_t)n * SEQ * SEQ + m0 * SEQ,
                     rhsT + (size_t)n * SEQ * DIM + n0 * SEQ,
                     out0 + (size_t)n * SEQ * 2 * DIM + DIM + m0 * 2 * DIM + n0,
                     rowpart + (size_t)n * 16 * SEQ + m0, sA, sB, sinv);
  } else {
    apply_body<false>(
        e_rT + (size_t)n * SEQ * SEQ + m0 * SEQ,
        lhsT + (size_t)n * SEQ * DIM + n0 * SEQ,
        out1 + (size_t)n * SEQ * 2 * DIM + DIM + m0 * 2 * DIM + n0,
        colpart + (size_t)n * 16 * SEQ + m0, sA, sB, sinv);
  }
}

// ---------------------------------------------------------------------------
extern "C" void kernel_launch(void* const* d_in, const int* in_sizes, int n_in,
                              void* d_out, int out_size, void* d_ws,
                              size_t ws_size, hipStream_t stream) {
  const float* lhs = (const float*)d_in[0];  // [8][1024][768]
  const float* rhs = (const float*)d_in[1];
  const float* Wl = (const float*)d_in[2];  // [768][768]
  const float* Wr = (const float*)d_in[3];
  float* out0 = (float*)d_out;  // [8][1024][1536]
  float* out1 = out0 + (size_t)NB * SEQ * (2 * DIM);

  // ws layout (stream-ordered lifetime reuse; peak ~85 MB):
  char* ws = (char*)d_ws;
  f16_t* lhsT = (f16_t*)(ws + 0);                           // ->apply
  unsigned short* rhsT = (unsigned short*)(ws + 12582912);  // bf16, ->apply
  f16_t* l_f = (f16_t*)(ws + 25165824);                     // dead after scores
  f16_t* r_f = (f16_t*)(ws + 37748736);                     // dead after scores
  f16_t* lhs_f = (f16_t*)(ws + 50331648);                   // dead after proj
  f16_t* rhs_f = (f16_t*)(ws + 62914560);                   // dead after proj
  f16_t* Wl_h = (f16_t*)(ws + 75497472);                    // dead after proj
  f16_t* Wr_h = (f16_t*)(ws + 76677120);
  unsigned short* e_l = (unsigned short*)(ws + 50331648);  // overlays lhs_f+
  f16_t* e_rT = (f16_t*)(ws + 67108864);                   // overlays rhs_f+W
  float* rowpart = (float*)(ws + 83886080);                // 512KB (16-way)
  float* colpart = (float*)(ws + 84410368);                // 512KB -> 84934656

  // 1. slim prep: fp16 casts only (batch==XCD decode for input blocks)
  prep<<<dim3(1680, 2), 256, 0, stream>>>(lhs, rhs, Wl, Wr, lhs_f, rhs_f,
                                          Wl_h, Wr_h);
  // 2. projections (async fp16 staging, batch==XCD)
  gemm_proj<<<768, 256, 0, stream>>>(lhs_f, Wl_h, rhs_f, Wr_h, l_f, r_f);
  // 3. scores (batch==XCD, L2-local) + XCD-aligned transpose riders
  scores_mix<<<768, 256, 0, stream>>>(l_f, r_f, lhs, rhs, e_l, e_rT, lhsT,
                                      rhsT, rowpart, colpart);
  // 4. applies (batch==XCD; normalizer + stats-finish in prologue/epilogue)
  //    + out-left copy riders (tail-fill, ids >= 768)
  gemm_apply<<<1024, 256, 0, stream>>>((const f16_t*)e_l, e_rT,
                                       (const f16_t*)rhsT, lhsT, rowpart,
                                       colpart, lhs, rhs, out0, out1);
}

// Round 6
// 233.911 us; speedup vs baseline: 1.0557x; 1.0557x over previous
//
#include <hip/hip_runtime.h>

typedef _Float16 f16_t;
typedef _Float16 f16x4 __attribute__((ext_vector_type(4)));
typedef _Float16 f16x8 __attribute__((ext_vector_type(8)));
typedef short s16x8 __attribute__((ext_vector_type(8)));
typedef unsigned short u16x4 __attribute__((ext_vector_type(4)));
typedef float floatx4 __attribute__((ext_vector_type(4)));

#define NB 8
#define SEQ 1024
#define DIM 768
// 1/sqrt(768)
#define INV_SCALE 0.03608439182435161f
// constant shift for unscaled row softmax (shift-invariant; row maxes ~35).
// e values are stored UNNORMALIZED in bf16 (fp32 exponent range -> no
// underflow for small row maxes); normalization happens in the apply epilogue.
#define ROW_SHIFT 40.0f

// float -> bf16 round-to-nearest-even
__device__ inline unsigned short f2bf(float f) {
  unsigned u = __builtin_bit_cast(unsigned, f);
  u += 0x7fffu + ((u >> 16) & 1u);
  return (unsigned short)(u >> 16);
}

// ---------------------------------------------------------------------------
// async 16B global->LDS; LDS dest = wave-uniform base + lane*16 (m104/m108).
__device__ inline void async_load16(const void* g, void* l) {
  __builtin_amdgcn_global_load_lds((__attribute__((address_space(1))) void*)g,
                                   (__attribute__((address_space(3))) void*)l,
                                   16, 0, 0);
}

// LDS bank-conflict XOR swizzle: logical column group (8 f16 = 16B) g of row
// r is stored at group g ^ (r&7). Async staging applies it to the *global
// source* column (dest is lane-forced); reads apply it to the LDS column.

// ---------------------------------------------------------------------------
// FAT prep: ONE read of each fp32 input tile fans out ALL derived products:
// (a) fp16 row-major cast (proj operand), (b) fp32 copy into output left
// half, (c) transposed fp16/bf16 copies (apply B operands). z>=16 -> W casts.
// Minimum-traffic arrangement (157 MB total); riders under GEMMs measured
// never-free (r4/r5 flat), so all glue streams here at full-machine BW.
__global__ __launch_bounds__(256) void prep(
    const float* __restrict__ lhs, const float* __restrict__ rhs,
    const float* __restrict__ Wl, const float* __restrict__ Wr,
    f16_t* __restrict__ lf, f16_t* __restrict__ rf, f16_t* __restrict__ lhsT,
    unsigned short* __restrict__ rhsT, f16_t* __restrict__ Wlh,
    f16_t* __restrict__ Wrh, float* __restrict__ o0, float* __restrict__ o1) {
  const int z = blockIdx.z;
  const int tid = threadIdx.x;
  const int x4 = (tid & 15) * 4, ty = tid >> 4;
  const int c0 = blockIdx.x * 64, r0 = blockIdx.y * 64;
  if (z >= 16) {  // W cast: [768][768], only 12 row-tiles
    if (blockIdx.y >= 12) return;
    const float* in = (z == 17 ? Wr : Wl);
    f16_t* out = (z == 17 ? Wrh : Wlh);
    #pragma unroll
    for (int it = 0; it < 4; ++it) {
      const int row = r0 + ty + it * 16;
      const float4 v = *(const float4*)&in[(size_t)row * DIM + c0 + x4];
      f16x4 h = {(f16_t)v.x, (f16_t)v.y, (f16_t)v.z, (f16_t)v.w};
      *(f16x4*)&out[(size_t)row * DIM + c0 + x4] = h;
    }
    return;
  }
  __shared__ float tile[64][65];
  const int n = z & 7;
  const float* in = (z < 8 ? lhs : rhs) + (size_t)n * SEQ * DIM;
  f16_t* fout = (z < 8 ? lf : rf) + (size_t)n * SEQ * DIM;
  float* oh = (z < 8 ? o0 : o1) + (size_t)n * SEQ * 2 * DIM;
  #pragma unroll
  for (int it = 0; it < 4; ++it) {
    const int row = ty + it * 16;
    const float4 v = *(const float4*)&in[(size_t)(r0 + row) * DIM + c0 + x4];
    f16x4 h = {(f16_t)v.x, (f16_t)v.y, (f16_t)v.z, (f16_t)v.w};
    *(f16x4*)&fout[(size_t)(r0 + row) * DIM + c0 + x4] = h;
    *(float4*)&oh[(size_t)(r0 + row) * 2 * DIM + c0 + x4] = v;
    tile[row][x4 + 0] = v.x;
    tile[row][x4 + 1] = v.y;
    tile[row][x4 + 2] = v.z;
    tile[row][x4 + 3] = v.w;
  }
  __syncthreads();
  if (z < 8) {
    f16_t* T = lhsT + (size_t)n * SEQ * DIM;  // [DIM][SEQ] fp16
    #pragma unroll
    for (int it = 0; it < 4; ++it) {
      const int cr = ty + it * 16;
      f16x4 o = {(f16_t)tile[x4 + 0][cr], (f16_t)tile[x4 + 1][cr],
                 (f16_t)tile[x4 + 2][cr], (f16_t)tile[x4 + 3][cr]};
      *(f16x4*)&T[(size_t)(c0 + cr) * SEQ + r0 + x4] = o;
    }
  } else {
    unsigned short* T = rhsT + (size_t)n * SEQ * DIM;  // [DIM][SEQ] bf16
    #pragma unroll
    for (int it = 0; it < 4; ++it) {
      const int cr = ty + it * 16;
      u16x4 o = {f2bf(tile[x4 + 0][cr]), f2bf(tile[x4 + 1][cr]),
                 f2bf(tile[x4 + 2][cr]), f2bf(tile[x4 + 3][cr])};
      *(u16x4*)&T[(size_t)(c0 + cr) * SEQ + r0 + x4] = o;
    }
  }
}

// ---------------------------------------------------------------------------
// Projection GEMM (plain fp16, async-staged): C = tanh(A[M,K] @ W[N,K]^T),
// fp16 out. Decode: batch n == XCD (b&7); j OUTER (8 consecutive blocks share
// one W panel -> stays L2-resident during its reuse window).
__global__ __launch_bounds__(256, 3) void gemm_proj(
    const f16_t* __restrict__ A0, const f16_t* __restrict__ W0,
    const f16_t* __restrict__ A1, const f16_t* __restrict__ W1,
    f16_t* __restrict__ C0, f16_t* __restrict__ C1) {
  __shared__ __align__(16) f16_t sA[128 * 64];
  __shared__ __align__(16) f16_t sB[128 * 64];
  const int b = blockIdx.x;  // 768 = 8n * 2side * 6j * 8myb
  const int n = b & 7;       // XCD
  const int s = b >> 3;      // 0..95
  const int side = s / 48;
  const int t = s - side * 48;
  const int j = t >> 3, myb = t & 7;  // j outer: W-panel reused 8x consecutive
  const int my = n * 8 + myb;         // rows of batch n
  const f16_t* Ab = (side ? A1 : A0) + (size_t)my * 128 * DIM;
  const f16_t* Bb = (side ? W1 : W0) + (size_t)j * 128 * DIM;
  f16_t* C = side ? C1 : C0;
  const int tid = threadIdx.x;
  const int lane = tid & 63;
  const int wave = tid >> 6;
  const int wr = wave >> 1, wc = wave & 1;
  const int fr = lane & 15;
  const int fq = lane >> 4;
  const int swz = ((lane & 7) ^ (lane >> 3)) << 3;  // staging src column
  const int x7 = (fr & 7) << 3;                     // read-side XOR

  floatx4 acc[4][4] = {};

  for (int kt = 0; kt < DIM; kt += 64) {
    #pragma unroll
    for (int i = 0; i < 4; ++i) {
      const int ch = i * 4 + wave;
      const int row = ch * 8 + (lane >> 3);
      const size_t g = (size_t)row * DIM + kt + swz;
      async_load16(Ab + g, (char*)sA + ch * 1024);
      async_load16(Bb + g, (char*)sB + ch * 1024);
    }
    __syncthreads();
    #pragma unroll
    for (int ks = 0; ks < 64; ks += 32) {
      f16x8 af[4], bf[4];
      #pragma unroll
      for (int t2 = 0; t2 < 4; ++t2) {
        const int cs = (ks + fq * 8) ^ x7;
        af[t2] = *(const f16x8*)&sA[(wr * 64 + t2 * 16 + fr) * 64 + cs];
        bf[t2] = *(const f16x8*)&sB[(wc * 64 + t2 * 16 + fr) * 64 + cs];
      }
      #pragma unroll
      for (int ti = 0; ti < 4; ++ti)
        #pragma unroll
        for (int tj = 0; tj < 4; ++tj)
          acc[ti][tj] = __builtin_amdgcn_mfma_f32_16x16x32_f16(
              af[ti], bf[tj], acc[ti][tj], 0, 0, 0);
    }
    __syncthreads();
  }

  // C/D layout (m89/m91): col = lane&15, row = (lane>>4)*4 + reg
  const size_t m0 = (size_t)my * 128, n0 = (size_t)j * 128;
  #pragma unroll
  for (int ti = 0; ti < 4; ++ti)
    #pragma unroll
    for (int tj = 0; tj < 4; ++tj) {
      const size_t gm = m0 + wr * 64 + ti * 16 + fq * 4;
      const size_t gn = n0 + wc * 64 + tj * 16 + fr;
      #pragma unroll
      for (int i = 0; i < 4; ++i) {
        // tanh(x) = 1 - 2/(e^{2x}+1); exact at +-inf, ~1ulp via v_rcp (fp16
        // output swallows the error). Avoids branchy libm tanhf.
        const float e = __expf(2.f * acc[ti][tj][i]);
        C[(gm + i) * DIM + gn] =
            (f16_t)(1.f - 2.f * __builtin_amdgcn_rcpf(e + 1.f));
      }
    }
}

// ---------------------------------------------------------------------------
// Scores GEMM (clean, 512 blocks): batch z == XCD; whole batch working set
// l_f[z]+r_f[z] = 3MB is L2-resident per XCD. Epilogue writes UNNORMALIZED
// exponentials: e_l bf16 row-major (direct), e_rT fp16 via LDS transpose
// (coalesced 16B stores), plus 16-way partial row/col sums (finished in
// gemm_apply's prologue).
__global__ __launch_bounds__(256, 3) void gemm_scores(
    const f16_t* __restrict__ A, const f16_t* __restrict__ B,
    unsigned short* __restrict__ e_l, f16_t* __restrict__ e_rT,
    float* __restrict__ rowpart, float* __restrict__ colpart) {
  __shared__ __align__(16) char smem[32768];
  const int b = blockIdx.x;
  const int tid = threadIdx.x;
  f16_t* sA = (f16_t*)smem;
  f16_t* sB = sA + 8192;
  const int z = b & 7;   // batch == XCD
  const int s = b >> 3;  // 0..63
  const int my = s >> 3, j = s & 7;
  const f16_t* Ab = A + (size_t)z * SEQ * DIM + (size_t)my * 128 * DIM;
  const f16_t* Bb = B + (size_t)z * SEQ * DIM + (size_t)j * 128 * DIM;
  const int lane = tid & 63;
  const int wave = tid >> 6;
  const int wr = wave >> 1, wc = wave & 1;
  const int fr = lane & 15;
  const int fq = lane >> 4;
  const int swz = ((lane & 7) ^ (lane >> 3)) << 3;
  const int x7 = (fr & 7) << 3;

  floatx4 acc[4][4] = {};

  for (int kt = 0; kt < DIM; kt += 64) {
    #pragma unroll
    for (int i = 0; i < 4; ++i) {
      const int ch = i * 4 + wave;
      const int row = ch * 8 + (lane >> 3);
      const size_t g = (size_t)row * DIM + kt + swz;
      async_load16(Ab + g, (char*)sA + ch * 1024);
      async_load16(Bb + g, (char*)sB + ch * 1024);
    }
    __syncthreads();
    #pragma unroll
    for (int ks = 0; ks < 64; ks += 32) {
      f16x8 af[4], bf[4];
      #pragma unroll
      for (int t2 = 0; t2 < 4; ++t2) {
        const int cs = (ks + fq * 8) ^ x7;
        af[t2] = *(const f16x8*)&sA[(wr * 64 + t2 * 16 + fr) * 64 + cs];
        bf[t2] = *(const f16x8*)&sB[(wc * 64 + t2 * 16 + fr) * 64 + cs];
      }
      #pragma unroll
      for (int ti = 0; ti < 4; ++ti)
        #pragma unroll
        for (int tj = 0; tj < 4; ++tj)
          acc[ti][tj] = __builtin_amdgcn_mfma_f32_16x16x32_f16(
              af[ti], bf[tj], acc[ti][tj], 0, 0, 0);
    }
    __syncthreads();
  }

  const size_t m0 = (size_t)my * 128, n0 = (size_t)j * 128;
  unsigned short* eL = e_l + (size_t)z * SEQ * SEQ;
  f16_t* eT = e_rT + (size_t)z * SEQ * SEQ;

  // row side: e = exp(s - 40) -> bf16 direct store (32B segments) + 16-way
  // partial row sums (axis: j*2+wc), stats entirely in registers.
  #pragma unroll
  for (int ti = 0; ti < 4; ++ti) {
    #pragma unroll
    for (int i = 0; i < 4; ++i) {
      const int rloc = wr * 64 + ti * 16 + fq * 4 + i;
      float sum = 0.f;
      #pragma unroll
      for (int tj = 0; tj < 4; ++tj) {
        const float e = __expf(acc[ti][tj][i] - ROW_SHIFT);
        sum += e;
        eL[(m0 + rloc) * SEQ + n0 + wc * 64 + tj * 16 + fr] = f2bf(e);
      }
      sum += __shfl_xor(sum, 1, 64);
      sum += __shfl_xor(sum, 2, 64);
      sum += __shfl_xor(sum, 4, 64);
      sum += __shfl_xor(sum, 8, 64);
      if (fr == 0)
        rowpart[((size_t)(z * 16 + j * 2 + wc)) * SEQ + m0 + rloc] = sum;
    }
  }
  // col side: e = exp(s * INV_SCALE) -> fp16 into LDS transpose tile
  // (XOR-swizzled), + 16-way partial col sums (axis: my*2+wr).
  #pragma unroll
  for (int tj = 0; tj < 4; ++tj) {
    const int rp = wc * 64 + tj * 16 + fr;  // e_rT-local row (= score col)
    float sum = 0.f;
    #pragma unroll
    for (int ti = 0; ti < 4; ++ti) {
      #pragma unroll
      for (int i = 0; i < 4; ++i) {
        const float e = __expf(acc[ti][tj][i] * INV_SCALE);
        sum += e;
        const int cp = wr * 64 + ti * 16 + fq * 4 + i;  // e_rT-local col
        *(f16_t*)(smem + rp * 256 + ((cp * 2) ^ ((rp & 7) << 4))) = (f16_t)e;
      }
    }
    sum += __shfl_xor(sum, 16, 64);
    sum += __shfl_xor(sum, 32, 64);
    if (fq == 0)
      colpart[((size_t)(z * 16 + my * 2 + wr)) * SEQ + n0 + rp] = sum;
  }
  __syncthreads();
  // coalesced e_rT store: 16 lanes cover one 256B row segment-pair
  #pragma unroll
  for (int it = 0; it < 8; ++it) {
    const int r = it * 16 + (tid >> 4), chunk = tid & 15;
    const f16x8 v =
        *(const f16x8*)(smem + r * 256 + ((chunk * 16) ^ ((r & 7) << 4)));
    *(f16x8*)&eT[(n0 + r) * SEQ + m0 + chunk * 8] = v;
  }
}

// ---------------------------------------------------------------------------
// Apply GEMM body. A = unnormalized exp matrix, B = transposed input, and the
// softmax normalizer (1/sum over 16 partials, per OUTPUT ROW) is applied in
// the epilogue. BF=true -> bf16 MFMA (side 0), else fp16 (side 1).
template <bool BF>
__device__ __forceinline__ void apply_body(
    const f16_t* __restrict__ Ab, const f16_t* __restrict__ Bb,
    float* __restrict__ C, const float* __restrict__ pp, f16_t* sA, f16_t* sB,
    float* sinv) {
  const int tid = threadIdx.x;
  const int lane = tid & 63;
  const int wave = tid >> 6;
  const int wr = wave >> 1, wc = wave & 1;
  const int fr = lane & 15;
  const int fq = lane >> 4;
  const int swz = ((lane & 7) ^ (lane >> 3)) << 3;
  const int x7 = (fr & 7) << 3;

  // finish stats here: 1/sum over 16 partials for this block's 128 out rows.
  if (tid < 128) {
    float s = 0.f;
    #pragma unroll
    for (int k = 0; k < 16; ++k) s += pp[k * SEQ + tid];
    sinv[tid] = 1.f / s;
  }

  floatx4 acc[4][4] = {};

  for (int kt = 0; kt < SEQ; kt += 64) {
    #pragma unroll
    for (int i = 0; i < 4; ++i) {
      const int ch = i * 4 + wave;
      const int row = ch * 8 + (lane >> 3);
      const size_t g = (size_t)row * SEQ + kt + swz;
      async_load16(Ab + g, (char*)sA + ch * 1024);
      async_load16(Bb + g, (char*)sB + ch * 1024);
    }
    __syncthreads();
    #pragma unroll
    for (int ks = 0; ks < 64; ks += 32) {
      const int cs = (ks + fq * 8) ^ x7;
      #pragma unroll
      for (int ti = 0; ti < 4; ++ti) {
        const f16_t* pa = &sA[(wr * 64 + ti * 16 + fr) * 64 + cs];
        #pragma unroll
        for (int tj = 0; tj < 4; ++tj) {
          const f16_t* pb = &sB[(wc * 64 + tj * 16 + fr) * 64 + cs];
          if constexpr (BF)
            acc[ti][tj] = __builtin_amdgcn_mfma_f32_16x16x32_bf16(
                *(const s16x8*)pa, *(const s16x8*)pb, acc[ti][tj], 0, 0, 0);
          else
            acc[ti][tj] = __builtin_amdgcn_mfma_f32_16x16x32_f16(
                *(const f16x8*)pa, *(const f16x8*)pb, acc[ti][tj], 0, 0, 0);
        }
      }
    }
    __syncthreads();
  }

  #pragma unroll
  for (int ti = 0; ti < 4; ++ti) {
    const int gm = wr * 64 + ti * 16 + fq * 4;
    const floatx4 iv = *(const floatx4*)&sinv[gm];
    #pragma unroll
    for (int tj = 0; tj < 4; ++tj) {
      const int gn = wc * 64 + tj * 16 + fr;
      #pragma unroll
      for (int i = 0; i < 4; ++i)
        C[(size_t)(gm + i) * (2 * DIM) + gn] = acc[ti][tj][i] * iv[i];
    }
  }
}

// Decode: batch n == XCD (b&7); both sides of batch n run on XCD n, reading
// e_l/e_rT[n] written there by scores (L2-warm). j OUTER (8 consecutive
// blocks share one B panel -> L2-resident during its reuse window).
__global__ __launch_bounds__(256, 3) void gemm_apply(
    const f16_t* __restrict__ e_l, const f16_t* __restrict__ e_rT,
    const f16_t* __restrict__ rhsT, const f16_t* __restrict__ lhsT,
    const float* __restrict__ rowpart, const float* __restrict__ colpart,
    float* __restrict__ out0, float* __restrict__ out1) {
  __shared__ __align__(16) f16_t sA[128 * 64];
  __shared__ __align__(16) f16_t sB[128 * 64];
  __shared__ __align__(16) float sinv[128];
  const int b = blockIdx.x;  // 768 = 8n * 2side * 6j * 8my
  const int n = b & 7;       // XCD
  const int s = b >> 3;      // 0..95
  const int side = s / 48;
  const int t = s - side * 48;
  const int j = t >> 3, my = t & 7;  // j outer: B-panel reused 8x consecutive
  const size_t m0 = (size_t)my * 128, n0 = (size_t)j * 128;
  if (side == 0) {
    apply_body<true>(e_l + (size_t)n * SEQ * SEQ + m0 * SEQ,
                     rhsT + (size_t)n * SEQ * DIM + n0 * SEQ,
                     out0 + (size_t)n * SEQ * 2 * DIM + DIM + m0 * 2 * DIM + n0,
                     rowpart + (size_t)n * 16 * SEQ + m0, sA, sB, sinv);
  } else {
    apply_body<false>(
        e_rT + (size_t)n * SEQ * SEQ + m0 * SEQ,
        lhsT + (size_t)n * SEQ * DIM + n0 * SEQ,
        out1 + (size_t)n * SEQ * 2 * DIM + DIM + m0 * 2 * DIM + n0,
        colpart + (size_t)n * 16 * SEQ + m0, sA, sB, sinv);
  }
}

// ---------------------------------------------------------------------------
extern "C" void kernel_launch(void* const* d_in, const int* in_sizes, int n_in,
                              void* d_out, int out_size, void* d_ws,
                              size_t ws_size, hipStream_t stream) {
  const float* lhs = (const float*)d_in[0];  // [8][1024][768]
  const float* rhs = (const float*)d_in[1];
  const float* Wl = (const float*)d_in[2];  // [768][768]
  const float* Wr = (const float*)d_in[3];
  float* out0 = (float*)d_out;  // [8][1024][1536]
  float* out1 = out0 + (size_t)NB * SEQ * (2 * DIM);

  // ws layout (stream-ordered lifetime reuse; peak ~85 MB):
  char* ws = (char*)d_ws;
  f16_t* lhsT = (f16_t*)(ws + 0);                           // ->apply
  unsigned short* rhsT = (unsigned short*)(ws + 12582912);  // bf16, ->apply
  f16_t* l_f = (f16_t*)(ws + 25165824);                     // dead after scores
  f16_t* r_f = (f16_t*)(ws + 37748736);                     // dead after scores
  f16_t* lhs_f = (f16_t*)(ws + 50331648);                   // dead after proj
  f16_t* rhs_f = (f16_t*)(ws + 62914560);                   // dead after proj
  f16_t* Wl_h = (f16_t*)(ws + 75497472);                    // dead after proj
  f16_t* Wr_h = (f16_t*)(ws + 76677120);
  unsigned short* e_l = (unsigned short*)(ws + 50331648);  // overlays lhs_f+
  f16_t* e_rT = (f16_t*)(ws + 67108864);                   // overlays rhs_f+W
  float* rowpart = (float*)(ws + 83886080);                // 512KB (16-way)
  float* colpart = (float*)(ws + 84410368);                // 512KB -> 84934656

  // 1. FAT prep: one read of fp32 inputs -> fp16 casts + transposes +
  //    output left halves + W casts (all glue, full-machine streaming)
  prep<<<dim3(12, 16, 18), 256, 0, stream>>>(lhs, rhs, Wl, Wr, lhs_f, rhs_f,
                                             lhsT, rhsT, Wl_h, Wr_h, out0,
                                             out1);
  // 2. projections (async fp16 staging, batch==XCD, j-outer W reuse)
  gemm_proj<<<768, 256, 0, stream>>>(lhs_f, Wl_h, rhs_f, Wr_h, l_f, r_f);
  // 3. scores (clean 512 blocks, batch==XCD, L2-local)
  gemm_scores<<<512, 256, 0, stream>>>(l_f, r_f, e_l, e_rT, rowpart, colpart);
  // 4. applies (clean 768 blocks, batch==XCD, j-outer B reuse)
  gemm_apply<<<768, 256, 0, stream>>>((const f16_t*)e_l, e_rT,
                                      (const f16_t*)rhsT, lhsT, rowpart,
                                      colpart, out0, out1);
}